// Round 1
// baseline (553.782 us; speedup 1.0000x reference)
//
#include <hip/hip_runtime.h>
#include <cstddef>

// Multigrid F-cycle advection, 4096^2 f32, T=4 outer iterations.
// Structure per iteration:
//   r1 = restrict(smooth(bc(v)))                 [fused: r0 never needed]
//   r2..r5 via restrict2 (two levels per kernel)
//   r6..r9 + up-sweep E9..E5 in ONE single-block LDS kernel
//   E4..E1 via k_up (zero-pad stencil on prolonged coarse e, + r)
//   v' = w - smooth(bc(w)), w = v - prolong(E1)  [fused final]

constexpr float CW = 0.05f;  // CXW == CYW == DT/DX/2

__device__ __forceinline__ float smooth_at(const float* __restrict__ v, int i, int j, int n) {
  // smooth(bc(v))[i,j] with replicate-edge BC (clamped indices).
  // Reference op order: CYW*up - CYW*down + CXW*left + center - CXW*right
  int iu = i > 0     ? i - 1 : 0;
  int id = i < n - 1 ? i + 1 : n - 1;
  int jl = j > 0     ? j - 1 : 0;
  int jr = j < n - 1 ? j + 1 : n - 1;
  float up = v[iu * n + j];
  float dn = v[id * n + j];
  float lf = v[i * n + jl];
  float ct = v[i * n + j];
  float rt = v[i * n + jr];
  return CW * up - CW * dn + CW * lf + ct - CW * rt;
}

// r1[I,J] = restrict(smooth(bc(v)))[I,J]; v: 4096^2 -> r1: 2048^2
__global__ void k_smooth_restrict(const float* __restrict__ v, float* __restrict__ r1) {
  int J = blockIdx.x * blockDim.x + threadIdx.x;
  int I = blockIdx.y * blockDim.y + threadIdx.y;
  const int n = 4096, h = 2048;
  float s00 = smooth_at(v, 2 * I,     2 * J,     n);  // even row, even col
  float s10 = smooth_at(v, 2 * I + 1, 2 * J,     n);  // odd  row, even col
  float s01 = smooth_at(v, 2 * I,     2 * J + 1, n);
  float s11 = smooth_at(v, 2 * I + 1, 2 * J + 1, n);
  r1[I * h + J] = 0.25f * (((s00 + s10) + s01) + s11);
}

// y = restrict(x) (n -> n/2), z = restrict(y) (n/2 -> n/4); one thread per z elem.
__global__ void k_restrict2(const float* __restrict__ x, float* __restrict__ y,
                            float* __restrict__ z, int n) {
  int J = blockIdx.x * blockDim.x + threadIdx.x;
  int I = blockIdx.y * blockDim.y + threadIdx.y;
  int h = n >> 1, q = n >> 2;
  if (I >= q || J >= q) return;
  float yv[2][2];
#pragma unroll
  for (int a = 0; a < 2; ++a)
#pragma unroll
    for (int b = 0; b < 2; ++b) {
      int yi = 2 * I + a, yj = 2 * J + b;
      float x00 = x[(2 * yi) * n + 2 * yj];
      float x10 = x[(2 * yi + 1) * n + 2 * yj];
      float x01 = x[(2 * yi) * n + 2 * yj + 1];
      float x11 = x[(2 * yi + 1) * n + 2 * yj + 1];
      float val = 0.25f * (((x00 + x10) + x01) + x11);
      y[yi * h + yj] = val;
      yv[a][b] = val;
    }
  z[I * q + J] = 0.25f * (((yv[0][0] + yv[1][0]) + yv[0][1]) + yv[1][1]);
}

// One element of: e_new = (P - smooth(pad(P_zero))) + r, where P = prolong(Ep)
// (zero padding, NOT replicate). Exactly the reference's rounding order.
__device__ __forceinline__ float up_elem(const float* Ep, const float* r, int i, int c, int n) {
  int s = n >> 1;
  float Pc = Ep[(i >> 1) * s + (c >> 1)];
  float Pu = (i > 0)     ? Ep[((i - 1) >> 1) * s + (c >> 1)] : 0.0f;
  float Pd = (i < n - 1) ? Ep[((i + 1) >> 1) * s + (c >> 1)] : 0.0f;
  float Pl = (c > 0)     ? Ep[(i >> 1) * s + ((c - 1) >> 1)] : 0.0f;
  float Pr = (c < n - 1) ? Ep[(i >> 1) * s + ((c + 1) >> 1)] : 0.0f;
  float sm = CW * Pu - CW * Pd + CW * Pl + Pc - CW * Pr;
  return (Pc - sm) + r[i * n + c];
}

__global__ void k_up(const float* __restrict__ Ep, const float* __restrict__ r,
                     float* __restrict__ Eo, int n) {
  int c = blockIdx.x * blockDim.x + threadIdx.x;
  int i = blockIdx.y * blockDim.y + threadIdx.y;
  if (i >= n || c >= n) return;
  Eo[i * n + c] = up_elem(Ep, r, i, c, n);
}

// Single-block kernel: r5 (128^2, global) -> r6..r9 (LDS), then E9=r9 and
// up-sweep E8,E7,E6 (LDS) -> E5 (128^2, global). Replaces 8 tiny launches.
__global__ void k_coarse(const float* __restrict__ r5, float* __restrict__ E5) {
  __shared__ float r6[64 * 64];
  __shared__ float r7[32 * 32];
  __shared__ float r8[16 * 16];
  __shared__ float r9[8 * 8];
  __shared__ float E8[16 * 16];
  __shared__ float E7[32 * 32];
  __shared__ float E6[64 * 64];
  int tid = threadIdx.x;
  int nt = blockDim.x;

  for (int idx = tid; idx < 64 * 64; idx += nt) {
    int I = idx >> 6, J = idx & 63;
    float a = r5[(2 * I) * 128 + 2 * J],     b = r5[(2 * I + 1) * 128 + 2 * J];
    float c = r5[(2 * I) * 128 + 2 * J + 1], d = r5[(2 * I + 1) * 128 + 2 * J + 1];
    r6[idx] = 0.25f * (((a + b) + c) + d);
  }
  __syncthreads();
  for (int idx = tid; idx < 32 * 32; idx += nt) {
    int I = idx >> 5, J = idx & 31;
    float a = r6[(2 * I) * 64 + 2 * J],     b = r6[(2 * I + 1) * 64 + 2 * J];
    float c = r6[(2 * I) * 64 + 2 * J + 1], d = r6[(2 * I + 1) * 64 + 2 * J + 1];
    r7[idx] = 0.25f * (((a + b) + c) + d);
  }
  __syncthreads();
  for (int idx = tid; idx < 16 * 16; idx += nt) {
    int I = idx >> 4, J = idx & 15;
    float a = r7[(2 * I) * 32 + 2 * J],     b = r7[(2 * I + 1) * 32 + 2 * J];
    float c = r7[(2 * I) * 32 + 2 * J + 1], d = r7[(2 * I + 1) * 32 + 2 * J + 1];
    r8[idx] = 0.25f * (((a + b) + c) + d);
  }
  __syncthreads();
  for (int idx = tid; idx < 8 * 8; idx += nt) {
    int I = idx >> 3, J = idx & 7;
    float a = r8[(2 * I) * 16 + 2 * J],     b = r8[(2 * I + 1) * 16 + 2 * J];
    float c = r8[(2 * I) * 16 + 2 * J + 1], d = r8[(2 * I + 1) * 16 + 2 * J + 1];
    r9[idx] = 0.25f * (((a + b) + c) + d);
  }
  __syncthreads();
  // E9 = r9 (e starts as zeros -> first up-step is exactly r9)
  for (int idx = tid; idx < 16 * 16; idx += nt)
    E8[idx] = up_elem(r9, r8, idx >> 4, idx & 15, 16);
  __syncthreads();
  for (int idx = tid; idx < 32 * 32; idx += nt)
    E7[idx] = up_elem(E8, r7, idx >> 5, idx & 31, 32);
  __syncthreads();
  for (int idx = tid; idx < 64 * 64; idx += nt)
    E6[idx] = up_elem(E7, r6, idx >> 6, idx & 63, 64);
  __syncthreads();
  for (int idx = tid; idx < 128 * 128; idx += nt)
    E5[idx] = up_elem(E6, r5, idx >> 7, idx & 127, 128);
}

// out = w - smooth(bc(w)), w = v - prolong(E1). E1: 2048^2, v/out: 4096^2.
__global__ void k_final(const float* __restrict__ v, const float* __restrict__ E1,
                        float* __restrict__ out) {
  int j = blockIdx.x * blockDim.x + threadIdx.x;
  int i = blockIdx.y * blockDim.y + threadIdx.y;
  const int n = 4096, h = 2048;
  int iu = i > 0     ? i - 1 : 0;
  int id = i < n - 1 ? i + 1 : n - 1;
  int jl = j > 0     ? j - 1 : 0;
  int jr = j < n - 1 ? j + 1 : n - 1;
  float wc = v[i * n + j]   - E1[(i >> 1) * h + (j >> 1)];
  float wu = v[iu * n + j]  - E1[(iu >> 1) * h + (j >> 1)];
  float wd = v[id * n + j]  - E1[(id >> 1) * h + (j >> 1)];
  float wl = v[i * n + jl]  - E1[(i >> 1) * h + (jl >> 1)];
  float wr = v[i * n + jr]  - E1[(i >> 1) * h + (jr >> 1)];
  float sm = CW * wu - CW * wd + CW * wl + wc - CW * wr;
  out[i * n + j] = wc - sm;
}

extern "C" void kernel_launch(void* const* d_in, const int* in_sizes, int n_in,
                              void* d_out, int out_size, void* d_ws, size_t ws_size,
                              hipStream_t stream) {
  (void)in_sizes; (void)n_in; (void)out_size;
  float* u = (float*)d_in[0];           // 4096^2 f32 (harness restores before each timed call)
  float* out = (float*)d_out;
  char* ws = (char*)d_ws;

  size_t off = 0;
  auto alloc = [&](size_t elems) {
    float* p = (float*)(ws + off);
    off += (elems * sizeof(float) + 255) & ~(size_t)255;
    return p;
  };
  float* r1 = alloc(2048 * 2048);
  float* r2 = alloc(1024 * 1024);
  float* r3 = alloc(512 * 512);
  float* r4 = alloc(256 * 256);
  float* r5 = alloc(128 * 128);
  float* E5 = alloc(128 * 128);
  float* E4 = alloc(256 * 256);
  float* E3 = alloc(512 * 512);
  float* E2 = alloc(1024 * 1024);
  float* E1 = alloc(2048 * 2048);
  size_t pool = off;
  const size_t VB = (size_t)4096 * 4096 * sizeof(float);
  bool big = ws_size >= pool + VB;      // room for a v ping-pong buffer?
  float* vws = (float*)(ws + pool);

  dim3 b(64, 4);
  auto iterate = [&](const float* vin, float* vout) {
    k_smooth_restrict<<<dim3(2048 / 64, 2048 / 4), b, 0, stream>>>(vin, r1);
    k_restrict2<<<dim3(512 / 64, 512 / 4), b, 0, stream>>>(r1, r2, r3, 2048);
    k_restrict2<<<dim3(128 / 64, 128 / 4), b, 0, stream>>>(r3, r4, r5, 512);
    k_coarse<<<1, 1024, 0, stream>>>(r5, E5);
    k_up<<<dim3(256 / 64, 256 / 4), b, 0, stream>>>(E5, r4, E4, 256);
    k_up<<<dim3(512 / 64, 512 / 4), b, 0, stream>>>(E4, r3, E3, 512);
    k_up<<<dim3(1024 / 64, 1024 / 4), b, 0, stream>>>(E3, r2, E2, 1024);
    k_up<<<dim3(2048 / 64, 2048 / 4), b, 0, stream>>>(E2, r1, E1, 2048);
    k_final<<<dim3(4096 / 64, 4096 / 4), b, 0, stream>>>(vin, E1, vout);
  };

  if (big) {
    iterate(u, vws);
    iterate(vws, out);
    iterate(out, vws);
    iterate(vws, out);               // final lands in d_out
  } else {
    // Fallback: ping-pong through d_in (restored by harness each launch).
    iterate(u, out);
    iterate(out, u);
    iterate(u, out);
    iterate(out, u);
    hipMemcpyAsync(out, u, VB, hipMemcpyDeviceToDevice, stream);
  }
}

// Round 2
// 397.913 us; speedup vs baseline: 1.3917x; 1.3917x over previous
//
#include <hip/hip_runtime.h>
#include <cstddef>

// Multigrid F-cycle advection, 4096^2 f32, T=4 outer iterations.
// R2: vectorized float4 loads/stores + register tiles everywhere.
// Per iteration:
//   r1 = restrict(smooth(bc(v)))                 [fused]
//   r2..r5 via k_restrict2 (two levels per kernel)
//   r6..r9 + up-sweep E9..E5 in ONE single-block LDS kernel
//   E4..E1 via k_up (zero-pad stencil on prolonged coarse e, + r)
//   v' = w - smooth(bc(w)), w = v - prolong(E1)  [fused final]

constexpr float CW = 0.05f;  // CXW == CYW == DT/DX/2

// e_new = (Pc - smooth_zero_pad(P)) + r, reference rounding order.
__device__ __forceinline__ float up_val(float Pc, float Pu, float Pd, float Pl,
                                        float Pr, float rv) {
  float sm = CW * Pu - CW * Pd + CW * Pl + Pc - CW * Pr;
  return (Pc - sm) + rv;
}

// ---------------------------------------------------------------------------
// r1 = restrict(smooth(bc(v))): v 4096^2 -> r1 2048^2.
// Thread computes a 2x2 output tile from a 6x6 register tile of v.
__global__ __launch_bounds__(256) void k_smooth_restrict(
    const float* __restrict__ v, float* __restrict__ r1) {
  const int n = 4096, h = 2048;
  int bj = blockIdx.x * blockDim.x + threadIdx.x;  // tile col 0..1023
  int bi = blockIdx.y * blockDim.y + threadIdx.y;  // tile row 0..1023
  int c0 = 4 * bj;
  int cl = max(c0 - 1, 0), cr = min(c0 + 4, n - 1);
  float a[6][6];
#pragma unroll
  for (int rr = 0; rr < 6; ++rr) {
    int R = min(max(4 * bi - 1 + rr, 0), n - 1);
    const float* row = v + (size_t)R * n;
    float4 m = *reinterpret_cast<const float4*>(row + c0);
    a[rr][0] = row[cl];
    a[rr][1] = m.x; a[rr][2] = m.y; a[rr][3] = m.z; a[rr][4] = m.w;
    a[rr][5] = row[cr];
  }
#pragma unroll
  for (int oi = 0; oi < 2; ++oi) {
    float2 o;
#pragma unroll
    for (int oj = 0; oj < 2; ++oj) {
      float s[2][2];
#pragma unroll
      for (int p = 0; p < 2; ++p)
#pragma unroll
        for (int q = 0; q < 2; ++q) {
          int P = 2 * oi + p, Q = 2 * oj + q;
          // CYW*up - CYW*down + CXW*left + center - CXW*right
          s[p][q] = CW * a[P][Q + 1] - CW * a[P + 2][Q + 1]
                  + CW * a[P + 1][Q] + a[P + 1][Q + 1] - CW * a[P + 1][Q + 2];
        }
      float val = 0.25f * (((s[0][0] + s[1][0]) + s[0][1]) + s[1][1]);
      (oj ? o.y : o.x) = val;
    }
    *reinterpret_cast<float2*>(r1 + (size_t)(2 * bi + oi) * h + 2 * bj) = o;
  }
}

// ---------------------------------------------------------------------------
// y = restrict(x) (n -> n/2), z = restrict(y) (n/2 -> n/4).
// Thread computes z(i, 2j..2j+1) from an 4x8 x-tile (8 float4 loads).
__global__ __launch_bounds__(256) void k_restrict2(
    const float* __restrict__ x, float* __restrict__ y,
    float* __restrict__ z, int n) {
  int h = n >> 1, q = n >> 2;
  int j = blockIdx.x * blockDim.x + threadIdx.x;  // z col-pair, j < q/2
  int i = blockIdx.y * blockDim.y + threadIdx.y;  // z row, i < q
  if (i >= q || 2 * j >= q) return;
  float xr[4][8];
#pragma unroll
  for (int rr = 0; rr < 4; ++rr) {
    const float* row = x + (size_t)(4 * i + rr) * n + 8 * j;
    float4 m0 = reinterpret_cast<const float4*>(row)[0];
    float4 m1 = reinterpret_cast<const float4*>(row)[1];
    xr[rr][0] = m0.x; xr[rr][1] = m0.y; xr[rr][2] = m0.z; xr[rr][3] = m0.w;
    xr[rr][4] = m1.x; xr[rr][5] = m1.y; xr[rr][6] = m1.z; xr[rr][7] = m1.w;
  }
  float yv[2][4];
#pragma unroll
  for (int a = 0; a < 2; ++a)
#pragma unroll
    for (int b = 0; b < 4; ++b)
      yv[a][b] = 0.25f * (((xr[2 * a][2 * b] + xr[2 * a + 1][2 * b])
                           + xr[2 * a][2 * b + 1]) + xr[2 * a + 1][2 * b + 1]);
#pragma unroll
  for (int a = 0; a < 2; ++a) {
    float4 o; o.x = yv[a][0]; o.y = yv[a][1]; o.z = yv[a][2]; o.w = yv[a][3];
    *reinterpret_cast<float4*>(y + (size_t)(2 * i + a) * h + 4 * j) = o;
  }
  float2 zo;
  zo.x = 0.25f * (((yv[0][0] + yv[1][0]) + yv[0][1]) + yv[1][1]);
  zo.y = 0.25f * (((yv[0][2] + yv[1][2]) + yv[0][3]) + yv[1][3]);
  *reinterpret_cast<float2*>(z + (size_t)i * q + 2 * j) = zo;
}

// ---------------------------------------------------------------------------
// Coarse-grid correction, one output 2x4 tile per thread.
// Ep needs only a 5-point cross: {epc0,epc1} center pair + l/r/u/d neighbors.
__global__ __launch_bounds__(256) void k_up(
    const float* __restrict__ Ep, const float* __restrict__ r,
    float* __restrict__ Eo, int n) {
  int s = n >> 1;
  int j = blockIdx.x * blockDim.x + threadIdx.x;  // out cols 4j..4j+3, j < n/4
  int i = blockIdx.y * blockDim.y + threadIdx.y;  // out rows 2i..2i+1, i < s
  if (i >= s || j >= (n >> 2)) return;
  const float* ec = Ep + (size_t)i * s + 2 * j;
  float epc0 = ec[0], epc1 = ec[1];
  float epl = (j > 0) ? ec[-1] : 0.0f;
  float epr = (2 * j + 2 < s) ? ec[2] : 0.0f;
  float epu0 = 0.0f, epu1 = 0.0f, epd0 = 0.0f, epd1 = 0.0f;
  if (i > 0)     { epu0 = ec[-s]; epu1 = ec[-s + 1]; }
  if (i < s - 1) { epd0 = ec[s];  epd1 = ec[s + 1]; }
  {
    float4 rv = *reinterpret_cast<const float4*>(r + (size_t)(2 * i) * n + 4 * j);
    float4 o;
    o.x = up_val(epc0, epu0, epc0, epl,  epc0, rv.x);
    o.y = up_val(epc0, epu0, epc0, epc0, epc1, rv.y);
    o.z = up_val(epc1, epu1, epc1, epc0, epc1, rv.z);
    o.w = up_val(epc1, epu1, epc1, epc1, epr,  rv.w);
    *reinterpret_cast<float4*>(Eo + (size_t)(2 * i) * n + 4 * j) = o;
  }
  {
    float4 rv = *reinterpret_cast<const float4*>(r + (size_t)(2 * i + 1) * n + 4 * j);
    float4 o;
    o.x = up_val(epc0, epc0, epd0, epl,  epc0, rv.x);
    o.y = up_val(epc0, epc0, epd0, epc0, epc1, rv.y);
    o.z = up_val(epc1, epc1, epd1, epc0, epc1, rv.z);
    o.w = up_val(epc1, epc1, epd1, epc1, epr,  rv.w);
    *reinterpret_cast<float4*>(Eo + (size_t)(2 * i + 1) * n + 4 * j) = o;
  }
}

// ---------------------------------------------------------------------------
// Single-block kernel: r5 (128^2) -> r6..r9 (LDS), then up-sweep E8..E6 -> E5.
__global__ void k_coarse(const float* __restrict__ r5, float* __restrict__ E5) {
  __shared__ float r6[64 * 64];
  __shared__ float r7[32 * 32];
  __shared__ float r8[16 * 16];
  __shared__ float r9[8 * 8];
  __shared__ float E8[16 * 16];
  __shared__ float E7[32 * 32];
  __shared__ float E6[64 * 64];
  int tid = threadIdx.x, nt = blockDim.x;

  auto up_lds = [&](const float* Ep, const float* rr, int i, int c, int nn) {
    int ss = nn >> 1;
    float Pc = Ep[(i >> 1) * ss + (c >> 1)];
    float Pu = (i > 0)      ? Ep[((i - 1) >> 1) * ss + (c >> 1)] : 0.0f;
    float Pd = (i < nn - 1) ? Ep[((i + 1) >> 1) * ss + (c >> 1)] : 0.0f;
    float Pl = (c > 0)      ? Ep[(i >> 1) * ss + ((c - 1) >> 1)] : 0.0f;
    float Pr = (c < nn - 1) ? Ep[(i >> 1) * ss + ((c + 1) >> 1)] : 0.0f;
    return up_val(Pc, Pu, Pd, Pl, Pr, rr[i * nn + c]);
  };

  for (int idx = tid; idx < 64 * 64; idx += nt) {
    int I = idx >> 6, J = idx & 63;
    float a = r5[(2 * I) * 128 + 2 * J],     b = r5[(2 * I + 1) * 128 + 2 * J];
    float c = r5[(2 * I) * 128 + 2 * J + 1], d = r5[(2 * I + 1) * 128 + 2 * J + 1];
    r6[idx] = 0.25f * (((a + b) + c) + d);
  }
  __syncthreads();
  for (int idx = tid; idx < 32 * 32; idx += nt) {
    int I = idx >> 5, J = idx & 31;
    float a = r6[(2 * I) * 64 + 2 * J],     b = r6[(2 * I + 1) * 64 + 2 * J];
    float c = r6[(2 * I) * 64 + 2 * J + 1], d = r6[(2 * I + 1) * 64 + 2 * J + 1];
    r7[idx] = 0.25f * (((a + b) + c) + d);
  }
  __syncthreads();
  for (int idx = tid; idx < 16 * 16; idx += nt) {
    int I = idx >> 4, J = idx & 15;
    float a = r7[(2 * I) * 32 + 2 * J],     b = r7[(2 * I + 1) * 32 + 2 * J];
    float c = r7[(2 * I) * 32 + 2 * J + 1], d = r7[(2 * I + 1) * 32 + 2 * J + 1];
    r8[idx] = 0.25f * (((a + b) + c) + d);
  }
  __syncthreads();
  for (int idx = tid; idx < 8 * 8; idx += nt) {
    int I = idx >> 3, J = idx & 7;
    float a = r8[(2 * I) * 16 + 2 * J],     b = r8[(2 * I + 1) * 16 + 2 * J];
    float c = r8[(2 * I) * 16 + 2 * J + 1], d = r8[(2 * I + 1) * 16 + 2 * J + 1];
    r9[idx] = 0.25f * (((a + b) + c) + d);
  }
  __syncthreads();
  for (int idx = tid; idx < 16 * 16; idx += nt)
    E8[idx] = up_lds(r9, r8, idx >> 4, idx & 15, 16);
  __syncthreads();
  for (int idx = tid; idx < 32 * 32; idx += nt)
    E7[idx] = up_lds(E8, r7, idx >> 5, idx & 31, 32);
  __syncthreads();
  for (int idx = tid; idx < 64 * 64; idx += nt)
    E6[idx] = up_lds(E7, r6, idx >> 6, idx & 63, 64);
  __syncthreads();
  for (int idx = tid; idx < 128 * 128; idx += nt)
    E5[idx] = up_lds(E6, r5, idx >> 7, idx & 127, 128);
}

// ---------------------------------------------------------------------------
// out = w - smooth(bc(w)), w = v - prolong(E1). Thread computes 2x4 outputs.
__global__ __launch_bounds__(256) void k_final(
    const float* __restrict__ v, const float* __restrict__ E1,
    float* __restrict__ out) {
  const int n = 4096, h = 2048;
  int J = blockIdx.x * blockDim.x + threadIdx.x;  // out cols 4J..4J+3, J < 1024
  int i = blockIdx.y * blockDim.y + threadIdx.y;  // out rows 2i..2i+1, i < 2048
  int c0 = 4 * J;
  int cl = max(c0 - 1, 0), cr = min(c0 + 4, n - 1);
  int ecl = cl >> 1, ecr = cr >> 1;

  // E1 rows: top=clamp(2i-1)>>1, mid=i, bot=clamp(2i+2)>>1
  float e[3][4];
  int ers0 = max(2 * i - 1, 0) >> 1;
  int ers2 = min(2 * i + 2, n - 1) >> 1;
  const int ers[3] = {ers0, i, ers2};
#pragma unroll
  for (int t = 0; t < 3; ++t) {
    const float* erow = E1 + (size_t)ers[t] * h;
    e[t][0] = erow[ecl];
    e[t][1] = erow[2 * J];
    e[t][2] = erow[2 * J + 1];
    e[t][3] = erow[ecr];
  }

  float w[4][6];
  const int tmap[4] = {0, 1, 1, 2};
#pragma unroll
  for (int rr = 0; rr < 4; ++rr) {
    int R = min(max(2 * i - 1 + rr, 0), n - 1);
    int t = tmap[rr];
    const float* vrow = v + (size_t)R * n;
    float4 m = *reinterpret_cast<const float4*>(vrow + c0);
    w[rr][0] = vrow[cl] - e[t][0];
    w[rr][1] = m.x - e[t][1];
    w[rr][2] = m.y - e[t][1];
    w[rr][3] = m.z - e[t][2];
    w[rr][4] = m.w - e[t][2];
    w[rr][5] = vrow[cr] - e[t][3];
  }
#pragma unroll
  for (int a = 0; a < 2; ++a) {
    float4 o;
#pragma unroll
    for (int qq = 0; qq < 4; ++qq) {
      float ce = w[a + 1][qq + 1];
      float sm = CW * w[a][qq + 1] - CW * w[a + 2][qq + 1]
               + CW * w[a + 1][qq] + ce - CW * w[a + 1][qq + 2];
      (&o.x)[qq] = ce - sm;
    }
    *reinterpret_cast<float4*>(out + (size_t)(2 * i + a) * n + c0) = o;
  }
}

// ---------------------------------------------------------------------------
extern "C" void kernel_launch(void* const* d_in, const int* in_sizes, int n_in,
                              void* d_out, int out_size, void* d_ws, size_t ws_size,
                              hipStream_t stream) {
  (void)in_sizes; (void)n_in; (void)out_size;
  float* u = (float*)d_in[0];
  float* out = (float*)d_out;
  char* ws = (char*)d_ws;

  size_t off = 0;
  auto alloc = [&](size_t elems) {
    float* p = (float*)(ws + off);
    off += (elems * sizeof(float) + 255) & ~(size_t)255;
    return p;
  };
  float* r1 = alloc(2048 * 2048);
  float* r2 = alloc(1024 * 1024);
  float* r3 = alloc(512 * 512);
  float* r4 = alloc(256 * 256);
  float* r5 = alloc(128 * 128);
  float* E5 = alloc(128 * 128);
  float* E4 = alloc(256 * 256);
  float* E3 = alloc(512 * 512);
  float* E2 = alloc(1024 * 1024);
  float* E1 = alloc(2048 * 2048);
  size_t pool = off;
  const size_t VB = (size_t)4096 * 4096 * sizeof(float);
  bool big = ws_size >= pool + VB;
  float* vws = (float*)(ws + pool);

  dim3 b(64, 4);
  auto iterate = [&](const float* vin, float* vout) {
    k_smooth_restrict<<<dim3(16, 256), b, 0, stream>>>(vin, r1);
    k_restrict2<<<dim3(4, 128), b, 0, stream>>>(r1, r2, r3, 2048);
    k_restrict2<<<dim3(1, 32), b, 0, stream>>>(r3, r4, r5, 512);
    k_coarse<<<1, 1024, 0, stream>>>(r5, E5);
    k_up<<<dim3(1, 32), b, 0, stream>>>(E5, r4, E4, 256);
    k_up<<<dim3(2, 64), b, 0, stream>>>(E4, r3, E3, 512);
    k_up<<<dim3(4, 128), b, 0, stream>>>(E3, r2, E2, 1024);
    k_up<<<dim3(8, 256), b, 0, stream>>>(E2, r1, E1, 2048);
    k_final<<<dim3(16, 512), b, 0, stream>>>(vin, E1, vout);
  };

  if (big) {
    iterate(u, vws);
    iterate(vws, out);
    iterate(out, vws);
    iterate(vws, out);
  } else {
    iterate(u, out);
    iterate(out, u);
    iterate(u, out);
    iterate(out, u);
    hipMemcpyAsync(out, u, VB, hipMemcpyDeviceToDevice, stream);
  }
}